// Round 11
// baseline (136.791 us; speedup 1.0000x reference)
//
#include <hip/hip_runtime.h>

#define IMH 512
#define IMW 512
#define TW 16
#define TH 8
#define HW_ (TW + 2)          // 18
#define HH_ (TH + 2)          // 10
#define NHALO (HW_ * HH_)     // 180
#define NPIX (TW * TH)        // 128 interior pixels per tile
#define ROW 31                // padded floats per halo pixel (30 ch + 1 pad; gcd(31,32)=1)

typedef float f4 __attribute__((ext_vector_type(4)));
typedef float f4a __attribute__((ext_vector_type(4), aligned(4)));
typedef float f2a __attribute__((ext_vector_type(2), aligned(4)));

// R11 = R10 (best, 105.09us) + two-tile software pipeline per block.
// Diagnosis: 2048 identical blocks launch in lockstep; all co-resident blocks
// are always in the SAME phase (A = HBM burst with idle VALU, then B = VALU/LDS
// with idle HBM), so pipes never overlap (kernel ~27.5us vs ~11us overlapped
// floor). Fix: each block runs two vertically adjacent tiles; ALL global loads
// (both tiles) issue up front — tile-1's HBM drain overlaps tile-0's whole
// B0+B1 compute, and A1 transforms from registers. B0/B1 bodies byte-identical
// to R10 (macro-parameterized by tile row). +34 VGPR held across B phases;
// static indexing throughout (anti-spill lessons R2/R5/R7).

// ---- load one halo pixel's inputs into registers (only when in-bounds)
#define LOADPX(HH, WW, WREG, OV, US, OK) {                                        \
    (OK) = !((HH) < 0 || (HH) >= IMH || (WW) < 0 || (WW) >= IMW);                 \
    if (OK) {                                                                     \
        const int pix_ = (HH) * IMW + (WW);                                       \
        const f2a o01_ = *(const f2a*)(obs + pix_ * 3);                           \
        (OV)[0] = o01_.x; (OV)[1] = o01_.y; (OV)[2] = obs[pix_ * 3 + 2];          \
        const f2a u01_ = *(const f2a*)(u_k + pix_ * 3);                           \
        (US)[0] = u01_.x; (US)[1] = u01_.y; (US)[2] = u_k[pix_ * 3 + 2];          \
        const float* wkp_ = &w_k[(size_t)pix_ * 27];                              \
        const f4a* v4_ = (const f4a*)wkp_;                                        \
        const f4a a0_ = v4_[0], a1_ = v4_[1], a2_ = v4_[2];                       \
        const f4a a3_ = v4_[3], a4_ = v4_[4], a5_ = v4_[5];                       \
        const f2a a6_ = *(const f2a*)(wkp_ + 24);                                 \
        (WREG)[0]=a0_.x;  (WREG)[1]=a0_.y;  (WREG)[2]=a0_.z;  (WREG)[3]=a0_.w;    \
        (WREG)[4]=a1_.x;  (WREG)[5]=a1_.y;  (WREG)[6]=a1_.z;  (WREG)[7]=a1_.w;    \
        (WREG)[8]=a2_.x;  (WREG)[9]=a2_.y;  (WREG)[10]=a2_.z; (WREG)[11]=a2_.w;   \
        (WREG)[12]=a3_.x; (WREG)[13]=a3_.y; (WREG)[14]=a3_.z; (WREG)[15]=a3_.w;   \
        (WREG)[16]=a4_.x; (WREG)[17]=a4_.y; (WREG)[18]=a4_.z; (WREG)[19]=a4_.w;   \
        (WREG)[20]=a5_.x; (WREG)[21]=a5_.y; (WREG)[22]=a5_.z; (WREG)[23]=a5_.w;   \
        (WREG)[24]=a6_.x; (WREG)[25]=a6_.y; (WREG)[26]=wkp_[26];                  \
    } }

// ---- Bayes update + sensitivity quotient rule -> LDS row P
#define TRANSFORM(OK, WREG, OV, US, PIDX) {                                       \
    float* row_ = &lds[(PIDX) * ROW];                                             \
    if (!(OK)) {                                                                  \
        _Pragma("unroll") for (int c = 0; c < 30; ++c) row_[c] = 0.0f;            \
    } else {                                                                      \
        float b_[3], Bu_[3], bu_ = 0.0f;                                          \
        _Pragma("unroll")                                                         \
        for (int s = 0; s < 3; ++s) {                                             \
            b_[s] = Pm[0 + s] * (OV)[0] + Pm[3 + s] * (OV)[1] + Pm[6 + s] * (OV)[2]; \
            Bu_[s] = b_[s] * (US)[s];                                             \
            bu_ += Bu_[s];                                                        \
        }                                                                         \
        const float inv_bu_ = 1.0f / bu_;                                         \
        float Z_[3];                                                              \
        _Pragma("unroll")                                                         \
        for (int s = 0; s < 3; ++s) { Z_[s] = Bu_[s] * inv_bu_; row_[s] = Z_[s]; }\
        _Pragma("unroll")                                                         \
        for (int i = 0; i < 3; ++i) {                                             \
            _Pragma("unroll")                                                     \
            for (int j = 0; j < 3; ++j) {                                         \
                const int ij_ = i * 3 + j;                                        \
                float du_[3], sdu_ = 0.0f;                                        \
                _Pragma("unroll")                                                 \
                for (int s = 0; s < 3; ++s) {                                     \
                    float d_ = b_[s] * (WREG)[s * 9 + ij_];                       \
                    if (s == j) d_ += (OV)[i] * (US)[s];                          \
                    du_[s] = d_;                                                  \
                    sdu_ += d_;                                                   \
                }                                                                 \
                _Pragma("unroll")                                                 \
                for (int s = 0; s < 3; ++s)                                       \
                    row_[(1 + ij_) * 3 + s] = (du_[s] - sdu_ * Z_[s]) * inv_bu_;  \
            }                                                                     \
        }                                                                         \
    } }

// ---- B0: per-pixel g0 conv + softmax -> u, p_aux; then group 9 conv+JVP
#define B0_BODY(H0T)                                                              \
    if (tid < NPIX) {                                                             \
        const int tx = tid & 15, ty = tid >> 4;                                   \
        const int hp = (ty + 1) * HW_ + (tx + 1);                                 \
        const int pix = ((H0T) + ty) * IMW + (w0 + tx);                           \
        float y0 = cb0, y1 = cb1, y2 = cb2;                                       \
        _Pragma("unroll")                                                         \
        for (int ky = 0; ky < 3; ++ky) {                                          \
            _Pragma("unroll")                                                     \
            for (int kx = 0; kx < 3; ++kx) {                                      \
                const float* nb = &lds[(hp + (ky - 1) * HW_ + (kx - 1)) * ROW];   \
                const float v0 = nb[0], v1 = nb[1], v2 = nb[2];                   \
                const int T = ky * 3 + kx;                                        \
                y0 += cw[0 + T] * v0 + cw[9 + T] * v1 + cw[18 + T] * v2;          \
                y1 += cw[27 + T] * v0 + cw[36 + T] * v1 + cw[45 + T] * v2;        \
                y2 += cw[54 + T] * v0 + cw[63 + T] * v1 + cw[72 + T] * v2;        \
            }                                                                     \
        }                                                                         \
        const float m_ = fmaxf(y0, fmaxf(y1, y2));                                \
        const float e0 = __expf(y0 - m_), e1 = __expf(y1 - m_), e2 = __expf(y2 - m_); \
        const float inv_ = 1.0f / (e0 + e1 + e2);                                 \
        const float p0 = e0 * inv_, p1 = e1 * inv_, p2 = e2 * inv_;               \
        out[pix * 3 + 0] = p0; out[pix * 3 + 1] = p1; out[pix * 3 + 2] = p2;      \
        p_aux4[tid] = (f4){p0, p1, p2, 0.0f};                                     \
        float a0 = 0.0f, a1 = 0.0f, a2 = 0.0f;                                    \
        _Pragma("unroll")                                                         \
        for (int ky = 0; ky < 3; ++ky) {                                          \
            _Pragma("unroll")                                                     \
            for (int kx = 0; kx < 3; ++kx) {                                      \
                const float* nb = &lds[(hp + (ky - 1) * HW_ + (kx - 1)) * ROW];   \
                const float v0 = nb[27], v1 = nb[28], v2 = nb[29];                \
                const int T = ky * 3 + kx;                                        \
                a0 += cw[0 + T] * v0 + cw[9 + T] * v1 + cw[18 + T] * v2;          \
                a1 += cw[27 + T] * v0 + cw[36 + T] * v1 + cw[45 + T] * v2;        \
                a2 += cw[54 + T] * v0 + cw[63 + T] * v1 + cw[72 + T] * v2;        \
            }                                                                     \
        }                                                                         \
        const float dot_ = p0 * a0 + p1 * a1 + p2 * a2;                           \
        float* wp = outw + (size_t)pix * 27;                                      \
        wp[8]  = p0 * (a0 - dot_);                                                \
        wp[17] = p1 * (a1 - dot_);                                                \
        wp[26] = p2 * (a2 - dot_);                                                \
    }

// ---- B1 row-walk machinery (identical math/order to R10)
#define ROWFMA(P0_, P1_, P2_, KY)                                                 \
    P0_ += cw[0 + (KY)*3 + 0] * v00 + cw[9 + (KY)*3 + 0] * v01 + cw[18 + (KY)*3 + 0] * v02; \
    P1_ += cw[27 + (KY)*3 + 0] * v00 + cw[36 + (KY)*3 + 0] * v01 + cw[45 + (KY)*3 + 0] * v02; \
    P2_ += cw[54 + (KY)*3 + 0] * v00 + cw[63 + (KY)*3 + 0] * v01 + cw[72 + (KY)*3 + 0] * v02; \
    P0_ += cw[0 + (KY)*3 + 1] * v10 + cw[9 + (KY)*3 + 1] * v11 + cw[18 + (KY)*3 + 1] * v12; \
    P1_ += cw[27 + (KY)*3 + 1] * v10 + cw[36 + (KY)*3 + 1] * v11 + cw[45 + (KY)*3 + 1] * v12; \
    P2_ += cw[54 + (KY)*3 + 1] * v10 + cw[63 + (KY)*3 + 1] * v11 + cw[72 + (KY)*3 + 1] * v12; \
    P0_ += cw[0 + (KY)*3 + 2] * v20 + cw[9 + (KY)*3 + 2] * v21 + cw[18 + (KY)*3 + 2] * v22; \
    P1_ += cw[27 + (KY)*3 + 2] * v20 + cw[36 + (KY)*3 + 2] * v21 + cw[45 + (KY)*3 + 2] * v22; \
    P2_ += cw[54 + (KY)*3 + 2] * v20 + cw[63 + (KY)*3 + 2] * v21 + cw[72 + (KY)*3 + 2] * v22;

#define FINISH(O, Q0, Q1, Q2) {                                                   \
    const f4 pv = p_aux4[(O) * 16 + x];                                           \
    const float dotf_ = pv.x * (Q0) + pv.y * (Q1) + pv.z * (Q2);                  \
    float* wp_ = outw + ((size_t)((h0t + (O)) * IMW + (w0 + x))) * 27 + ij;       \
    wp_[0]  = pv.x * ((Q0) - dotf_);                                              \
    wp_[9]  = pv.y * ((Q1) - dotf_);                                              \
    wp_[18] = pv.z * ((Q2) - dotf_); }

#define STEP(R, N0,N1,N2, M0,M1,M2, O0,O1,O2, DO_N, DO_M, DO_O) {                 \
    const int rb = ((rowb + (R)) * HW_ + x) * ROW + gch;                          \
    const float v00 = lds[rb + 0],  v01 = lds[rb + 1],  v02 = lds[rb + 2];        \
    const float v10 = lds[rb + 31], v11 = lds[rb + 32], v12 = lds[rb + 33];       \
    const float v20 = lds[rb + 62], v21 = lds[rb + 63], v22 = lds[rb + 64];       \
    if (DO_N) { N0 = 0.0f; N1 = 0.0f; N2 = 0.0f; ROWFMA(N0, N1, N2, 0) }          \
    if (DO_M) { ROWFMA(M0, M1, M2, 1) }                                           \
    if (DO_O) { ROWFMA(O0, O1, O2, 2) FINISH(rowb + (R) - 2, O0, O1, O2) } }

#define B1_BODY(H0T) {                                                            \
    const int h0t = (H0T);                                                        \
    const int x = tid & 15;                                                       \
    const int g = ((tid >> 4) & 7) + 1;                                           \
    const int ij = g - 1;                                                         \
    const int gch = 3 * g;                                                        \
    const int hlf = tid >> 7;                                                     \
    const int rowb = hlf * 4;                                                     \
    float a00, a01, a02, b10, b11, b12, c20, c21, c22;                            \
    STEP(0, a00,a01,a02, b10,b11,b12, c20,c21,c22, true,  false, false)           \
    STEP(1, b10,b11,b12, a00,a01,a02, c20,c21,c22, true,  true,  false)           \
    STEP(2, c20,c21,c22, b10,b11,b12, a00,a01,a02, true,  true,  true )           \
    STEP(3, a00,a01,a02, c20,c21,c22, b10,b11,b12, true,  true,  true )           \
    STEP(4, b10,b11,b12, a00,a01,a02, c20,c21,c22, false, true,  true )           \
    STEP(5, c20,c21,c22, b10,b11,b12, a00,a01,a02, false, false, true )           \
    }

__global__ __launch_bounds__(256, 4)
void hmm_fused(const float* __restrict__ obs,
               const float* __restrict__ P,      // (S,O) indexed P[o*3+s]
               const float* __restrict__ u_k,
               const float* __restrict__ w_k,    // pix*27 + s*9 + i*3 + j
               const float* __restrict__ conv_w, // (S_out,S_in,3,3)
               const float* __restrict__ conv_b, // (S,)
               float* __restrict__ out) {        // [0, 512*512*3): u ; rest: w
    __shared__ __align__(16) float lds[NHALO * ROW];   // 22,320 B
    __shared__ f4 p_aux4[NPIX];                        // 2,048 B

    const int tid = threadIdx.x;
    const int w0 = blockIdx.x * TW;
    const int h0a = blockIdx.y * (2 * TH);             // tile 0 rows
    const int h0b = h0a + TH;                          // tile 1 rows

    float Pm[9];
#pragma unroll
    for (int i = 0; i < 9; ++i) Pm[i] = P[i];
    float cw[81];                                      // uniform -> SGPRs
#pragma unroll
    for (int i = 0; i < 81; ++i) cw[i] = conv_w[i];
    const float cb0 = conv_b[0], cb1 = conv_b[1], cb2 = conv_b[2];

    float* outw = out + IMH * IMW * 3;

    // tile-1 prefetch state (lives across tile-0's B phases)
    float wreg1[27], ov1[3], us1[3];
    bool ok1 = false;

    // ---------- front-load ALL global reads, then transform tile 0
    if (tid < NHALO) {
        const int ph = tid / HW_ - 1, pw = tid % HW_ - 1;
        float wreg0[27], ov0[3], us0[3];
        bool ok0;
        LOADPX(h0a + ph, w0 + pw, wreg0, ov0, us0, ok0)
        LOADPX(h0b + ph, w0 + pw, wreg1, ov1, us1, ok1)   // in flight through B0/B1
        TRANSFORM(ok0, wreg0, ov0, us0, tid)
    }
    __syncthreads();

    // ---------- tile 0 compute (tile-1 HBM drain overlaps this)
    B0_BODY(h0a)
    __syncthreads();
    B1_BODY(h0a)
    __syncthreads();

    // ---------- tile 1: transform from registers (no new global latency)
    if (tid < NHALO) { TRANSFORM(ok1, wreg1, ov1, us1, tid) }
    __syncthreads();

    B0_BODY(h0b)
    __syncthreads();
    B1_BODY(h0b)
}

extern "C" void kernel_launch(void* const* d_in, const int* in_sizes, int n_in,
                              void* d_out, int out_size, void* d_ws, size_t ws_size,
                              hipStream_t stream) {
    const float* obs    = (const float*)d_in[0];
    const float* P      = (const float*)d_in[1];
    const float* u_k    = (const float*)d_in[2];
    const float* w_k    = (const float*)d_in[3];
    const float* conv_w = (const float*)d_in[4];
    const float* conv_b = (const float*)d_in[5];
    float* out = (float*)d_out;

    dim3 grid(IMW / TW, IMH / (2 * TH));   // (32, 32) = 1024 blocks, 2 tiles each
    hmm_fused<<<grid, 256, 0, stream>>>(obs, P, u_k, w_k, conv_w, conv_b, out);
}

// Round 12
// 108.579 us; speedup vs baseline: 1.2598x; 1.2598x over previous
//
#include <hip/hip_runtime.h>

#define IMH 512
#define IMW 512
#define TW 16
#define TH 8
#define HW_ (TW + 2)          // 18
#define HH_ (TH + 2)          // 10
#define NHALO (HW_ * HH_)     // 180
#define NPIX (TW * TH)        // 128 interior pixels per block
#define ROW 31                // padded floats per halo pixel (30 ch + 1 pad; gcd(31,32)=1)

typedef float f4 __attribute__((ext_vector_type(4)));
typedef float f4a __attribute__((ext_vector_type(4), aligned(4)));
typedef float f2a __attribute__((ext_vector_type(2), aligned(4)));

// R12 = R10 verbatim (measured best: 105.09us). R11's two-tile pipeline
// regressed via the now-4x-confirmed allocator behavior (R2/R5/R7/R11):
// holding >~50 floats across phase boundaries => VGPR cap 64 + ~110MB scratch.
// R9's kernel split regressed via intermediate round-trip traffic. This
// structure — fused, 2 thr/px stage B, row-walk partial-sum conv, 3 rotating
// accumulator triplets, direct stores — is the practical plateau: VALU/LDS/HBM
// each ~1/3 busy, no pipe saturable, phase overlap blocked on both sides.
//   B0 (128 thr, 1/px): g0 conv + softmax -> u, p_aux; then group-9 conv+JVP.
//   B1 (256 thr = 16 cols x 8 groups x 2 row-halves): rows 0-5 -> outs 0-3,
//       rows 4-9 -> outs 4-7, via 3 rotating pending accumulator triplets.
// FMA order per output: ky chronological, kx-inner, ch-inner (bit-stable).
__global__ __launch_bounds__(256, 4)
void hmm_fused(const float* __restrict__ obs,
               const float* __restrict__ P,      // (S,O) indexed P[o*3+s] per einsum 'os,hwo->hws'
               const float* __restrict__ u_k,
               const float* __restrict__ w_k,    // (H,W,S,1,S,O) -> pix*27 + s*9 + i*3 + j
               const float* __restrict__ conv_w, // (S_out,S_in,3,3)
               const float* __restrict__ conv_b, // (S,)
               float* __restrict__ out) {        // [0, 512*512*3): u_kp1 ; rest: w_kp1_O
    __shared__ __align__(16) float lds[NHALO * ROW];   // 22,320 B
    __shared__ f4 p_aux4[NPIX];                        // 2,048 B (p0,p1,p2,pad)

    const int tid = threadIdx.x;
    const int w0 = blockIdx.x * TW;
    const int h0 = blockIdx.y * TH;

    // P into registers (wave-uniform -> SGPRs)
    float Pm[9];
#pragma unroll
    for (int i = 0; i < 9; ++i) Pm[i] = P[i];

    // ---------- Stage A: halo pixels -> Z (ch 0..2) and w_pre (ch 3..29) in LDS
    if (tid < NHALO) {
        const int p = tid;
        const int hh = h0 + p / HW_ - 1;
        const int ww = w0 + p % HW_ - 1;
        float* row = &lds[p * ROW];
        if (hh < 0 || hh >= IMH || ww < 0 || ww >= IMW) {
#pragma unroll
            for (int c = 0; c < 30; ++c) row[c] = 0.0f;   // SAME zero padding
        } else {
            const int pix = hh * IMW + ww;

            const f2a o01 = *(const f2a*)(obs + pix * 3);
            const float o2 = obs[pix * 3 + 2];
            const f2a u01 = *(const f2a*)(u_k + pix * 3);
            const float u2 = u_k[pix * 3 + 2];
            const float ov[3] = {o01.x, o01.y, o2};
            const float us[3] = {u01.x, u01.y, u2};

            // w_k slice: 27 floats as 6x float4 + float2 + float
            const float* wkp = &w_k[(size_t)pix * 27];
            float wreg[27];
            {
                const f4a* v4 = (const f4a*)wkp;
                const f4a a0 = v4[0], a1 = v4[1], a2 = v4[2], a3 = v4[3], a4 = v4[4], a5 = v4[5];
                const f2a a6 = *(const f2a*)(wkp + 24);
                const float a7 = wkp[26];
                wreg[0] = a0.x;  wreg[1] = a0.y;  wreg[2] = a0.z;  wreg[3] = a0.w;
                wreg[4] = a1.x;  wreg[5] = a1.y;  wreg[6] = a1.z;  wreg[7] = a1.w;
                wreg[8] = a2.x;  wreg[9] = a2.y;  wreg[10] = a2.z; wreg[11] = a2.w;
                wreg[12] = a3.x; wreg[13] = a3.y; wreg[14] = a3.z; wreg[15] = a3.w;
                wreg[16] = a4.x; wreg[17] = a4.y; wreg[18] = a4.z; wreg[19] = a4.w;
                wreg[20] = a5.x; wreg[21] = a5.y; wreg[22] = a5.z; wreg[23] = a5.w;
                wreg[24] = a6.x; wreg[25] = a6.y; wreg[26] = a7;
            }

            float b[3], Bu[3], bu = 0.0f;
#pragma unroll
            for (int s = 0; s < 3; ++s) {
                b[s] = Pm[0 * 3 + s] * ov[0] + Pm[1 * 3 + s] * ov[1] + Pm[2 * 3 + s] * ov[2];
                Bu[s] = b[s] * us[s];
                bu += Bu[s];
            }
            const float inv_bu = 1.0f / bu;
            float Z[3];
#pragma unroll
            for (int s = 0; s < 3; ++s) { Z[s] = Bu[s] * inv_bu; row[s] = Z[s]; }

#pragma unroll
            for (int i = 0; i < 3; ++i) {
#pragma unroll
                for (int j = 0; j < 3; ++j) {
                    const int ij = i * 3 + j;
                    float du[3], sdu = 0.0f;
#pragma unroll
                    for (int s = 0; s < 3; ++s) {
                        float d = b[s] * wreg[s * 9 + ij];
                        if (s == j) d += ov[i] * us[s];
                        du[s] = d;
                        sdu += d;
                    }
#pragma unroll
                    for (int s = 0; s < 3; ++s)
                        row[(1 + ij) * 3 + s] = (du[s] - sdu * Z[s]) * inv_bu;
                }
            }
        }
    }

    // conv weights/bias (wave-uniform loads -> SGPRs). cw[s*27 + c*9 + ky*3 + kx]
    float cw[81];
#pragma unroll
    for (int i = 0; i < 81; ++i) cw[i] = conv_w[i];
    const float cb0 = conv_b[0], cb1 = conv_b[1], cb2 = conv_b[2];

    __syncthreads();

    float* outw = out + IMH * IMW * 3;

    // ---------- Stage B0: one thread per pixel: g0 conv + softmax -> u, p_aux;
    // then group 9 (ij=8) conv + JVP + store (fills B0's idle tail).
    if (tid < NPIX) {
        const int tx = tid & 15, ty = tid >> 4;
        const int hp = (ty + 1) * HW_ + (tx + 1);
        const int pix = (h0 + ty) * IMW + (w0 + tx);
        float y0 = cb0, y1 = cb1, y2 = cb2;
#pragma unroll
        for (int ky = 0; ky < 3; ++ky) {
#pragma unroll
            for (int kx = 0; kx < 3; ++kx) {
                const float* nb = &lds[(hp + (ky - 1) * HW_ + (kx - 1)) * ROW];
                const float v0 = nb[0], v1 = nb[1], v2 = nb[2];
                const int T = ky * 3 + kx;
                y0 += cw[0 + T] * v0 + cw[9 + T] * v1 + cw[18 + T] * v2;
                y1 += cw[27 + T] * v0 + cw[36 + T] * v1 + cw[45 + T] * v2;
                y2 += cw[54 + T] * v0 + cw[63 + T] * v1 + cw[72 + T] * v2;
            }
        }
        const float m = fmaxf(y0, fmaxf(y1, y2));
        const float e0 = __expf(y0 - m), e1 = __expf(y1 - m), e2 = __expf(y2 - m);
        const float inv = 1.0f / (e0 + e1 + e2);
        const float p0 = e0 * inv, p1 = e1 * inv, p2 = e2 * inv;
        out[pix * 3 + 0] = p0; out[pix * 3 + 1] = p1; out[pix * 3 + 2] = p2;
        p_aux4[tid] = (f4){p0, p1, p2, 0.0f};

        // group 9 (lds channels 27..29), same FMA order as the row-walk
        float a0 = 0.0f, a1 = 0.0f, a2 = 0.0f;
#pragma unroll
        for (int ky = 0; ky < 3; ++ky) {
#pragma unroll
            for (int kx = 0; kx < 3; ++kx) {
                const float* nb = &lds[(hp + (ky - 1) * HW_ + (kx - 1)) * ROW];
                const float v0 = nb[27], v1 = nb[28], v2 = nb[29];
                const int T = ky * 3 + kx;
                a0 += cw[0 + T] * v0 + cw[9 + T] * v1 + cw[18 + T] * v2;
                a1 += cw[27 + T] * v0 + cw[36 + T] * v1 + cw[45 + T] * v2;
                a2 += cw[54 + T] * v0 + cw[63 + T] * v1 + cw[72 + T] * v2;
            }
        }
        const float dot_ = p0 * a0 + p1 * a1 + p2 * a2;
        float* wp = outw + (size_t)pix * 27;
        wp[8]  = p0 * (a0 - dot_);
        wp[17] = p1 * (a1 - dot_);
        wp[26] = p2 * (a2 - dot_);
    }

    __syncthreads();

    // ---------- Stage B1: 256 threads = 16 cols x 8 groups x 2 row-halves.
    // Each walks 6 halo rows (base = half*4), producing 4 output rows via 3
    // rotating pending accumulator triplets (ky=0 newest, ky=1, ky=2 completes).
    {
        const int x = tid & 15;                 // tile column
        const int g = ((tid >> 4) & 7) + 1;     // JVP group 1..8
        const int ij = g - 1;
        const int gch = 3 * g;                  // LDS channel offset
        const int half = tid >> 7;
        const int rowb = half * 4;              // halo-row base: 0 or 4

        float a00, a01, a02;   // pending triplet A
        float b10, b11, b12;   // pending triplet B
        float c20, c21, c22;   // pending triplet C

#define ROWFMA(P0_, P1_, P2_, KY)                                                        \
        P0_ += cw[0 + (KY)*3 + 0] * v00 + cw[9 + (KY)*3 + 0] * v01 + cw[18 + (KY)*3 + 0] * v02; \
        P1_ += cw[27 + (KY)*3 + 0] * v00 + cw[36 + (KY)*3 + 0] * v01 + cw[45 + (KY)*3 + 0] * v02; \
        P2_ += cw[54 + (KY)*3 + 0] * v00 + cw[63 + (KY)*3 + 0] * v01 + cw[72 + (KY)*3 + 0] * v02; \
        P0_ += cw[0 + (KY)*3 + 1] * v10 + cw[9 + (KY)*3 + 1] * v11 + cw[18 + (KY)*3 + 1] * v12; \
        P1_ += cw[27 + (KY)*3 + 1] * v10 + cw[36 + (KY)*3 + 1] * v11 + cw[45 + (KY)*3 + 1] * v12; \
        P2_ += cw[54 + (KY)*3 + 1] * v10 + cw[63 + (KY)*3 + 1] * v11 + cw[72 + (KY)*3 + 1] * v12; \
        P0_ += cw[0 + (KY)*3 + 2] * v20 + cw[9 + (KY)*3 + 2] * v21 + cw[18 + (KY)*3 + 2] * v22; \
        P1_ += cw[27 + (KY)*3 + 2] * v20 + cw[36 + (KY)*3 + 2] * v21 + cw[45 + (KY)*3 + 2] * v22; \
        P2_ += cw[54 + (KY)*3 + 2] * v20 + cw[63 + (KY)*3 + 2] * v21 + cw[72 + (KY)*3 + 2] * v22;

#define FINISH(O, Q0, Q1, Q2) {                                                          \
        const f4 pv = p_aux4[(O) * 16 + x];                                              \
        const float dot_ = pv.x * (Q0) + pv.y * (Q1) + pv.z * (Q2);                      \
        float* wp = outw + ((size_t)((h0 + (O)) * IMW + (w0 + x))) * 27 + ij;            \
        wp[0]  = pv.x * ((Q0) - dot_);                                                   \
        wp[9]  = pv.y * ((Q1) - dot_);                                                   \
        wp[18] = pv.z * ((Q2) - dot_); }

        // DO_N/DO_M/DO_O compile-time -> dead branches fold away. R is relative
        // to rowb (runtime base; only LDS/aux addressing, rotation stays static).
#define STEP(R, N0,N1,N2, M0,M1,M2, O0,O1,O2, DO_N, DO_M, DO_O) {                        \
        const int rb = ((rowb + (R)) * HW_ + x) * ROW + gch;                             \
        const float v00 = lds[rb + 0],  v01 = lds[rb + 1],  v02 = lds[rb + 2];           \
        const float v10 = lds[rb + 31], v11 = lds[rb + 32], v12 = lds[rb + 33];          \
        const float v20 = lds[rb + 62], v21 = lds[rb + 63], v22 = lds[rb + 64];          \
        if (DO_N) { N0 = 0.0f; N1 = 0.0f; N2 = 0.0f; ROWFMA(N0, N1, N2, 0) }             \
        if (DO_M) { ROWFMA(M0, M1, M2, 1) }                                              \
        if (DO_O) { ROWFMA(O0, O1, O2, 2) FINISH(rowb + (R) - 2, O0, O1, O2) } }

        STEP(0, a00,a01,a02, b10,b11,b12, c20,c21,c22, true,  false, false)  // A:=r0
        STEP(1, b10,b11,b12, a00,a01,a02, c20,c21,c22, true,  true,  false)  // B:=r1; A ky1
        STEP(2, c20,c21,c22, b10,b11,b12, a00,a01,a02, true,  true,  true )  // C:=r2; B ky1; A fin(out0)
        STEP(3, a00,a01,a02, c20,c21,c22, b10,b11,b12, true,  true,  true )  // A:=r3; C ky1; B fin(out1)
        STEP(4, b10,b11,b12, a00,a01,a02, c20,c21,c22, false, true,  true )  // A ky1; C fin(out2)
        STEP(5, c20,c21,c22, b10,b11,b12, a00,a01,a02, false, false, true )  // A fin(out3)

#undef STEP
#undef FINISH
#undef ROWFMA
    }
}

extern "C" void kernel_launch(void* const* d_in, const int* in_sizes, int n_in,
                              void* d_out, int out_size, void* d_ws, size_t ws_size,
                              hipStream_t stream) {
    const float* obs    = (const float*)d_in[0];
    const float* P      = (const float*)d_in[1];
    const float* u_k    = (const float*)d_in[2];
    const float* w_k    = (const float*)d_in[3];
    const float* conv_w = (const float*)d_in[4];
    const float* conv_b = (const float*)d_in[5];
    float* out = (float*)d_out;

    dim3 grid(IMW / TW, IMH / TH);   // (32, 64) = 2048 blocks
    hmm_fused<<<grid, 256, 0, stream>>>(obs, P, u_k, w_k, conv_w, conv_b, out);
}